// Round 7
// baseline (633.959 us; speedup 1.0000x reference)
//
#include <hip/hip_runtime.h>

typedef __bf16 bf16x8 __attribute__((ext_vector_type(8)));
typedef __bf16 bf16x4 __attribute__((ext_vector_type(4)));
typedef float  f32x4  __attribute__((ext_vector_type(4)));

__device__ __forceinline__ bf16x8 ldb8(const __bf16* p) {
    return *reinterpret_cast<const bf16x8*>(p);
}
__device__ __forceinline__ bf16x8 zero8() {
    bf16x8 z;
    #pragma unroll
    for (int i = 0; i < 8; i++) z[i] = (__bf16)0.f;
    return z;
}
// mode m: 0 = storage is bf16, 1 = storage is fp32
__device__ __forceinline__ __bf16 ldw(const void* p, int i, int m) {
    return m ? (__bf16)((const float*)p)[i] : ((const __bf16*)p)[i];
}
__device__ __forceinline__ bf16x8 ldx8(const void* p, size_t ei, int m) {
    if (m) {
        const float* f = (const float*)p + ei;
        f32x4 a = *reinterpret_cast<const f32x4*>(f);
        f32x4 b = *reinterpret_cast<const f32x4*>(f + 4);
        bf16x8 r;
        #pragma unroll
        for (int u = 0; u < 4; u++) { r[u] = (__bf16)a[u]; r[4 + u] = (__bf16)b[u]; }
        return r;
    }
    return ldb8((const __bf16*)p + ei);
}

// ---------------- detect: input dtype + mask expand (64 blocks) ----------------
__global__ __launch_bounds__(256) void detect_kernel(
    const void* x, const void* mask, int* modes, int* maskws)
{
    __shared__ int v32bad, v16bad, sbad;
    const int t = threadIdx.x, bid = blockIdx.x;
    if (t == 0) { v32bad = 0; v16bad = 0; sbad = 0; }
    __syncthreads();
    const unsigned int* mw = (const unsigned int*)mask;
    int b32 = 0, b16 = 0;
    for (int i = t; i < 10496; i += 256) {
        unsigned int w = mw[i];
        if (!(w == 0u || w == 1u || w == 0x3F800000u)) b32++;
        unsigned int h0 = w & 0xFFFFu, h1 = w >> 16;
        if (!(h0 == 0u || h0 == 1u || h0 == 0x3F80u)) b16++;
        if (!(h1 == 0u || h1 == 1u || h1 == 0x3F80u)) b16++;
    }
    if (b32) atomicAdd(&v32bad, b32);
    if (b16) atomicAdd(&v16bad, b16);
    if (bid == 0) {
        const unsigned int* xw = (const unsigned int*)x;
        int bad = 0;
        for (int i = t; i < 2048; i += 256) {
            unsigned int w = xw[i];
            unsigned int el = (w >> 7) & 0xFF, eh = (w >> 23) & 0xFF;
            if (el >= 0x94 || el == 0xFF) bad++;
            if (eh >= 0x94 || eh == 0xFF) bad++;
        }
        if (bad) atomicAdd(&sbad, bad);
    }
    __syncthreads();
    const int mmode = (v32bad == 0) ? 0 : ((v16bad == 0) ? 2 : 1);
    if (bid == 0 && t == 0) { modes[0] = (sbad > 64) ? 1 : 0; modes[1] = mmode; }
    const int lo = bid * 656, hi = lo + 656;   // 64*656 = 41984
    for (int i = lo + t; i < hi; i += 256) {
        int val;
        if (mmode == 0)      val = (((const int*)mask)[i] != 0);
        else if (mmode == 2) val = (((const unsigned short*)mask)[i] != 0);
        else                 val = (((const unsigned char*)mask)[i] != 0);
        maskws[i] = val;
    }
}

// ---------------- prep: transpose/pad weights into ws (mode-aware) ----------------
// Wts/Wtq: (768 x 256)  rows 0..511 = w_qk^T (q|k), rows 512..767 = w_v^T
// w1t: (4 x 64 x 128)  w1[e]^T zero-padded (n<50, k<100)
// w2t: (4 x 112 x 64)  w2[e]^T zero-padded (n<100, k<50)
// wot: (256 x 256)     w_out^T
// wsm: [0:128)=w_gate [128:132)=b_gate [132:136)=ln_g [136:140)=ln_b
//      [140:340)=b1 [340:740)=b2 [740:996)=b_out
__global__ __launch_bounds__(256) void prep_kernel(
    const void* wqks, const void* wqkq, const void* wv, const void* w1,
    const void* w2, const void* wout, const void* wg, const void* bg,
    const void* lng, const void* lnb, const void* b1, const void* b2,
    const void* bout, const int* __restrict__ modes,
    __bf16* __restrict__ Wts, __bf16* __restrict__ Wtq,
    __bf16* __restrict__ w1t, __bf16* __restrict__ w2t,
    __bf16* __restrict__ wot, __bf16* __restrict__ wsm)
{
    const int m = modes[0];
    int i = blockIdx.x * 256 + threadIdx.x;
    if (i < 196608) {
        int n = i >> 8, k = i & 255;
        __bf16 vs, vq;
        if (n < 512) { vs = ldw(wqks, k * 512 + n, m); vq = ldw(wqkq, k * 512 + n, m); }
        else         { vs = ldw(wv, k * 256 + (n - 512), m); vq = vs; }
        Wts[i] = vs; Wtq[i] = vq;
        return;
    }
    i -= 196608;
    if (i < 32768) {
        int e = i >> 13, r = i & 8191, n = r >> 7, k = r & 127;
        w1t[i] = (n < 50 && k < 100) ? ldw(w1, (e * 100 + k) * 50 + n, m) : (__bf16)0.f;
        return;
    }
    i -= 32768;
    if (i < 28672) {
        int e = i / 7168, r = i % 7168, n = r >> 6, k = r & 63;
        w2t[i] = (n < 100 && k < 50) ? ldw(w2, (e * 50 + k) * 100 + n, m) : (__bf16)0.f;
        return;
    }
    i -= 28672;
    if (i < 65536) {
        int n = i >> 8, k = i & 255;
        wot[i] = ldw(wout, k * 256 + n, m);
        return;
    }
    i -= 65536;
    if (i < 996) {
        __bf16 v;
        if (i < 128)      v = ldw(wg, i, m);
        else if (i < 132) v = ldw(bg, i - 128, m);
        else if (i < 136) v = ldw(lng, i - 132, m);
        else if (i < 140) v = ldw(lnb, i - 136, m);
        else if (i < 340) v = ldw(b1, i - 140, m);
        else if (i < 740) v = ldw(b2, i - 340, m);
        else              v = ldw(bout, i - 740, m);
        wsm[i] = v;
    }
}

// ---------------- qkv projection GEMM + fused gate ----------------
__global__ __launch_bounds__(256, 2) void qkv_kernel(
    const void* __restrict__ x, const __bf16* __restrict__ Wts,
    const __bf16* __restrict__ Wtq, const __bf16* __restrict__ wsm,
    const int* __restrict__ modes,
    __bf16* __restrict__ q, __bf16* __restrict__ k, __bf16* __restrict__ v,
    float* __restrict__ gates)
{
    __shared__ __bf16 xs[32][264];
    __shared__ float wgf[128];
    __shared__ float gcst[12];
    const int m = modes[0];
    const int b = blockIdx.y;
    const int mt = blockIdx.x;
    const __bf16* Wt = (mt < 4) ? Wts : Wtq;
    const int rbase = (mt < 4) ? mt * 32 : 100 + (mt - 4) * 32;
    const int tid = threadIdx.x;

    if (tid < 128) wgf[tid] = (float)wsm[tid];
    if (tid < 12)  gcst[tid] = (float)wsm[128 + tid];
    for (int c = tid; c < 1024; c += 256) {
        int row = c >> 5, part = c & 31;
        bf16x8 val = ldx8(x, ((size_t)b * 164 + rbase + row) * 256 + part * 8, m);
        *reinterpret_cast<bf16x8*>(&xs[row][part * 8]) = val;
    }
    __syncthreads();

    // ---- fused gate ----
    {
        int jg = rbase * 8 + tid;
        int h = jg / 164;
        int j = jg - h * 164;
        if (j < 100) {
            const __bf16* xp = &xs[tid >> 3][(tid & 7) * 32];
            float g[4] = {gcst[0], gcst[1], gcst[2], gcst[3]};
            #pragma unroll
            for (int p = 0; p < 4; p++) {
                bf16x8 xv = ldb8(xp + p * 8);
                #pragma unroll
                for (int u = 0; u < 8; u++) {
                    float f = (float)xv[u];
                    #pragma unroll
                    for (int e = 0; e < 4; e++) g[e] += f * wgf[(p * 8 + u) * 4 + e];
                }
            }
            float mu = 0.25f * (g[0] + g[1] + g[2] + g[3]);
            float var = 0.25f * ((g[0]-mu)*(g[0]-mu) + (g[1]-mu)*(g[1]-mu) +
                                 (g[2]-mu)*(g[2]-mu) + (g[3]-mu)*(g[3]-mu));
            float is = rsqrtf(var + 1e-5f);
            float mx = -3.0e38f;
            #pragma unroll
            for (int e = 0; e < 4; e++) {
                g[e] = (g[e] - mu) * is * gcst[4 + e] + gcst[8 + e];
                mx = fmaxf(mx, g[e]);
            }
            float s = 0.f;
            #pragma unroll
            for (int e = 0; e < 4; e++) { g[e] = __expf(g[e] - mx); s += g[e]; }
            float inv = 1.f / s;
            float4 gv = make_float4(g[0]*inv, g[1]*inv, g[2]*inv, g[3]*inv);
            *reinterpret_cast<float4*>(&gates[((size_t)(b * 8 + h) * 100 + j) * 4]) = gv;
        }
    }

    const int w = tid >> 6, l = tid & 63, lr = l & 15, lc = l >> 4;
    f32x4 acc[2][12];
    #pragma unroll
    for (int ms = 0; ms < 2; ms++)
        #pragma unroll
        for (int nt = 0; nt < 12; nt++) acc[ms][nt] = (f32x4){0.f, 0.f, 0.f, 0.f};

    #pragma unroll
    for (int kt = 0; kt < 8; kt++) {
        bf16x8 a0 = ldb8(&xs[lr][kt * 32 + lc * 8]);
        bf16x8 a1 = ldb8(&xs[16 + lr][kt * 32 + lc * 8]);
        #pragma unroll
        for (int nt = 0; nt < 12; nt++) {
            bf16x8 bb = ldb8(Wt + (size_t)(w * 192 + nt * 16 + lr) * 256 + kt * 32 + lc * 8);
            acc[0][nt] = __builtin_amdgcn_mfma_f32_16x16x32_bf16(a0, bb, acc[0][nt], 0, 0, 0);
            acc[1][nt] = __builtin_amdgcn_mfma_f32_16x16x32_bf16(a1, bb, acc[1][nt], 0, 0, 0);
        }
    }
    #pragma unroll
    for (int ms = 0; ms < 2; ms++) {
        #pragma unroll
        for (int nt = 0; nt < 12; nt++) {
            int c = w * 192 + nt * 16 + lr;
            __bf16* dst; int ch;
            if (c < 256)      { dst = q; ch = c; }
            else if (c < 512) { dst = k; ch = c - 256; }
            else              { dst = v; ch = c - 512; }
            int hh = ch >> 5, d = ch & 31;
            #pragma unroll
            for (int r = 0; r < 4; r++) {
                int i = rbase + ms * 16 + lc * 4 + r;
                if (mt >= 4 || i < 100)
                    dst[(((size_t)b * 8 + hh) * 164 + i) * 32 + d] = (__bf16)acc[ms][nt][r];
            }
        }
    }
}

// ---------------- fused attention v5: single-barrier, K from global ----------------
// LDS 39424 B:
//   [0)      Vt[32][200]                              12800 B
//   [6400)   reluS[64][136] + h1s[64][72] (MoE)  \ union with
//   [6400)   P[64][200] (probs, post-barrier)    /    26624 B
__global__ __launch_bounds__(256, 4) void attn_kernel(
    const __bf16* __restrict__ qg, const __bf16* __restrict__ kg,
    const __bf16* __restrict__ vg, const float* __restrict__ gatesg,
    const int* __restrict__ maskg, const __bf16* __restrict__ w1t,
    const __bf16* __restrict__ w2t, const __bf16* __restrict__ wsm,
    __bf16* __restrict__ ohg)
{
    __shared__ __align__(16) __bf16 lds[19712];
    const int R2 = 6400;      // reluS base (stride 136) / P base (stride 200)
    const int H1 = 15104;     // h1s base (stride 72)

    const __bf16* b1g = wsm + 140;
    const __bf16* b2g = wsm + 340;
    const int bh = blockIdx.x, rt = blockIdx.y, b = bh >> 3, tid = threadIdx.x;
    const int w = tid >> 6, l = tid & 63, lr = l & 15, lc = l >> 4;
    const int m0 = w * 16;

    // ---- prefetch q-frag + mask bits ----
    int qrow = rt * 64 + m0 + lr; if (qrow > 163) qrow = 163;
    bf16x8 afq = ldb8(qg + ((size_t)bh * 164 + qrow) * 32 + lc * 8);
    unsigned mbits = 0;
    #pragma unroll
    for (int nt = 0; nt < 11; nt++) {
        int j = nt * 16 + lr;
        int bad = (j < 164) ? maskg[b * 164 + j] : 1;
        mbits |= (bad ? 1u : 0u) << nt;
    }

    // ---- QK^T: B-frags straight from global K (row-major == B-layout) ----
    const __bf16* kbase = kg + (size_t)bh * 164 * 32;
    f32x4 raw[12];
    #pragma unroll
    for (int nt = 0; nt < 11; nt++) {
        bf16x8 bf = ldb8(kbase + (size_t)(nt * 16 + lr) * 32 + lc * 8);
        f32x4 acc = {0.f, 0.f, 0.f, 0.f};
        acc = __builtin_amdgcn_mfma_f32_16x16x32_bf16(afq, bf, acc, 0, 0, 0);
        bool bad = (mbits >> nt) & 1;
        #pragma unroll
        for (int r = 0; r < 4; r++)
            raw[nt][r] = bad ? -1e30f : acc[r] * 0.0625f;
    }
    #pragma unroll
    for (int r = 0; r < 4; r++) raw[11][r] = -1e30f;

    // ---- reluS (wave-private rows, stride 136) — no barrier needed ----
    #pragma unroll
    for (int nt = 0; nt < 8; nt++) {
        int j = nt * 16 + lr;
        #pragma unroll
        for (int r = 0; r < 4; r++) {
            float v = raw[nt][r];
            v = (j >= 100 || v < 0.f) ? 0.f : v;
            lds[R2 + (m0 + lc * 4 + r) * 136 + j] = (__bf16)v;
        }
    }

    // ---- stage V^T now; latency overlaps the whole MoE ----
    const __bf16* vbase = vg + (size_t)bh * 164 * 32;
    {
        int dd = tid & 31;
        #pragma unroll
        for (int p = 0; p < 3; p++) {
            int j0 = ((tid >> 5) + p * 8) * 8;
            bf16x8 vv = zero8();
            if (j0 < 164) {
                #pragma unroll
                for (int u = 0; u < 8; u++)
                    if (j0 + u < 164) vv[u] = vbase[(size_t)(j0 + u) * 32 + dd];
            }
            *reinterpret_cast<bf16x8*>(&lds[dd * 200 + j0]) = vv;
        }
    }

    // ---- MoE: accumulate straight into raw (rows < 100) ----
    if (rt < 2) {
        const int gi0 = rt * 64 + m0 + lc * 4;
        float gt[4][4];
        #pragma unroll
        for (int e = 0; e < 4; e++)
            #pragma unroll
            for (int r = 0; r < 4; r++)
                gt[e][r] = (gi0 + r < 100) ? gatesg[((size_t)bh * 100 + gi0 + r) * 4 + e] : 0.f;

        for (int e = 0; e < 4; e++) {
            bf16x8 sa[4];
            #pragma unroll
            for (int kt = 0; kt < 4; kt++)
                sa[kt] = ldb8(&lds[R2 + (m0 + lr) * 136 + kt * 32 + lc * 8]);
            #pragma unroll
            for (int nt = 0; nt < 4; nt++) {
                f32x4 acc = {0.f, 0.f, 0.f, 0.f};
                #pragma unroll
                for (int kt = 0; kt < 4; kt++) {
                    bf16x8 bb = ldb8(w1t + (size_t)(e * 64 + nt * 16 + lr) * 128 + kt * 32 + lc * 8);
                    acc = __builtin_amdgcn_mfma_f32_16x16x32_bf16(sa[kt], bb, acc, 0, 0, 0);
                }
                int n = nt * 16 + lr;
                float bias = (n < 50) ? (float)b1g[e * 50 + n] : 0.f;
                #pragma unroll
                for (int r = 0; r < 4; r++) {
                    float v = acc[r] + bias;
                    if (v < 0.f) v = 0.f;
                    lds[H1 + (m0 + lc * 4 + r) * 72 + n] = (__bf16)v;
                }
            }
            bf16x8 ha0 = ldb8(&lds[H1 + (m0 + lr) * 72 + lc * 8]);
            bf16x8 ha1 = ldb8(&lds[H1 + (m0 + lr) * 72 + 32 + lc * 8]);
            #pragma unroll
            for (int nt = 0; nt < 7; nt++) {
                f32x4 acc = {0.f, 0.f, 0.f, 0.f};
                bf16x8 bb0 = ldb8(w2t + (size_t)(e * 112 + nt * 16 + lr) * 64 + lc * 8);
                acc = __builtin_amdgcn_mfma_f32_16x16x32_bf16(ha0, bb0, acc, 0, 0, 0);
                bf16x8 bb1 = ldb8(w2t + (size_t)(e * 112 + nt * 16 + lr) * 64 + 32 + lc * 8);
                acc = __builtin_amdgcn_mfma_f32_16x16x32_bf16(ha1, bb1, acc, 0, 0, 0);
                int n = nt * 16 + lr;
                float bias = (n < 100) ? (float)b2g[e * 100 + n] : 0.f;
                #pragma unroll
                for (int r = 0; r < 4; r++) {
                    float v = acc[r] + bias;
                    if (v < 0.f) v = 0.f;
                    raw[nt][r] += v * gt[e][r];
                }
            }
        }
    }
    __syncthreads();   // single barrier: MoE regions dead, Vt staged (vmcnt drain)

    // ---- in-register softmax; write probs P (stride 200, own rows) ----
    #pragma unroll
    for (int r = 0; r < 4; r++) {
        float m2 = -3.0e38f;
        #pragma unroll
        for (int nt = 0; nt < 12; nt++) m2 = fmaxf(m2, raw[nt][r]);
        m2 = fmaxf(m2, __shfl_xor(m2, 1, 64));
        m2 = fmaxf(m2, __shfl_xor(m2, 2, 64));
        m2 = fmaxf(m2, __shfl_xor(m2, 4, 64));
        m2 = fmaxf(m2, __shfl_xor(m2, 8, 64));
        float s2 = 0.f;
        #pragma unroll
        for (int nt = 0; nt < 12; nt++) {
            float ev = __expf(raw[nt][r] - m2);
            raw[nt][r] = ev;
            s2 += ev;
        }
        s2 += __shfl_xor(s2, 1, 64);
        s2 += __shfl_xor(s2, 2, 64);
        s2 += __shfl_xor(s2, 4, 64);
        s2 += __shfl_xor(s2, 8, 64);
        float inv = (s2 > 0.f) ? 1.f / s2 : 0.f;
        #pragma unroll
        for (int nt = 0; nt < 12; nt++)
            lds[R2 + (m0 + lc * 4 + r) * 200 + nt * 16 + lr] = (__bf16)(raw[nt][r] * inv);
    }

    // ---- O^T = V^T @ P^T (all reads wave-private or post-barrier Vt) ----
    int gi = rt * 64 + m0 + lr;
    #pragma unroll
    for (int nt = 0; nt < 2; nt++) {
        f32x4 acc = {0.f, 0.f, 0.f, 0.f};
        #pragma unroll
        for (int kt = 0; kt < 6; kt++) {
            bf16x8 va = ldb8(&lds[(nt * 16 + lr) * 200 + kt * 32 + lc * 8]);
            bf16x8 pb = ldb8(&lds[R2 + (m0 + lr) * 200 + kt * 32 + lc * 8]);
            acc = __builtin_amdgcn_mfma_f32_16x16x32_bf16(va, pb, acc, 0, 0, 0);
        }
        if (gi < 164) {
            bf16x4 ov;
            #pragma unroll
            for (int r = 0; r < 4; r++) ov[r] = (__bf16)acc[r];
            *reinterpret_cast<bf16x4*>(&ohg[((size_t)bh * 164 + gi) * 32 + nt * 16 + lc * 4]) = ov;
        }
    }
}

// ---------------- output projection (writes fp32) ----------------
__global__ __launch_bounds__(256) void outproj_kernel(
    const __bf16* __restrict__ oh, const __bf16* __restrict__ wot,
    const __bf16* __restrict__ wsm, float* __restrict__ out)
{
    const __bf16* bout = wsm + 740;
    const int b = blockIdx.y;
    const int mt = blockIdx.x >> 1;
    const int ntile = blockIdx.x & 1;
    const int tid = threadIdx.x;
    const int w = tid >> 6, l = tid & 63, lr = l & 15, lc = l >> 4;
    int row = mt * 64 + w * 16 + lr; if (row > 163) row = 163;
    f32x4 acc[8];
    #pragma unroll
    for (int nt = 0; nt < 8; nt++) acc[nt] = (f32x4){0.f, 0.f, 0.f, 0.f};
    #pragma unroll
    for (int kt = 0; kt < 8; kt++) {
        bf16x8 a = ldb8(oh + (((size_t)b * 8 + kt) * 164 + row) * 32 + lc * 8);
        #pragma unroll
        for (int nt = 0; nt < 8; nt++) {
            bf16x8 bb = ldb8(wot + (size_t)(ntile * 128 + nt * 16 + lr) * 256 + kt * 32 + lc * 8);
            acc[nt] = __builtin_amdgcn_mfma_f32_16x16x32_bf16(a, bb, acc[nt], 0, 0, 0);
        }
    }
    #pragma unroll
    for (int nt = 0; nt < 8; nt++) {
        int n = ntile * 128 + nt * 16 + lr;
        float bias = (float)bout[n];
        #pragma unroll
        for (int r = 0; r < 4; r++) {
            int i = mt * 64 + w * 16 + lc * 4 + r;
            if (i < 164)
                out[((size_t)b * 164 + i) * 256 + n] = acc[nt][r] + bias;
        }
    }
}

extern "C" void kernel_launch(void* const* d_in, const int* in_sizes, int n_in,
                              void* d_out, int out_size, void* d_ws, size_t ws_size,
                              hipStream_t stream) {
    const void* x      = d_in[0];
    const void* mask   = d_in[1];
    const void* w_qk_s = d_in[2];
    const void* w_qk_q = d_in[3];
    const void* w_v    = d_in[4];
    const void* w_gate = d_in[5];
    const void* b_gate = d_in[6];
    const void* ln_g   = d_in[7];
    const void* ln_b   = d_in[8];
    const void* w1     = d_in[9];
    const void* b1     = d_in[10];
    const void* w2     = d_in[11];
    const void* b2     = d_in[12];
    const void* w_out  = d_in[13];
    const void* b_out  = d_in[14];
    float* out = (float*)d_out;

    char* ws = (char*)d_ws;
    size_t off = 0;
    auto nextp = [&](size_t bytes) {
        char* p = ws + off;
        off += (bytes + 255) & ~(size_t)255;
        return p;
    };
    const size_t QKV_ELEMS = (size_t)256 * 8 * 164 * 32;   // 10,747,904
    int*    modes  = (int*)nextp(64);
    int*    maskws = (int*)nextp((size_t)41984 * 4);
    __bf16* qws  = (__bf16*)nextp(QKV_ELEMS * 2);
    __bf16* kws  = (__bf16*)nextp(QKV_ELEMS * 2);
    __bf16* vws  = (__bf16*)nextp(QKV_ELEMS * 2);
    __bf16* ohws = (__bf16*)nextp(QKV_ELEMS * 2);
    float*  gws  = (float*)nextp((size_t)2048 * 100 * 4 * 4);
    __bf16* Wts  = (__bf16*)nextp(768 * 256 * 2);
    __bf16* Wtq  = (__bf16*)nextp(768 * 256 * 2);
    __bf16* w1t  = (__bf16*)nextp(4 * 64 * 128 * 2);
    __bf16* w2t  = (__bf16*)nextp(4 * 112 * 64 * 2);
    __bf16* wot  = (__bf16*)nextp(256 * 256 * 2);
    __bf16* wsm  = (__bf16*)nextp(996 * 2);

    detect_kernel<<<64, 256, 0, stream>>>(x, mask, modes, maskws);
    prep_kernel<<<1268, 256, 0, stream>>>(w_qk_s, w_qk_q, w_v, w1, w2, w_out,
                                          w_gate, b_gate, ln_g, ln_b, b1, b2,
                                          b_out, modes, Wts, Wtq, w1t, w2t, wot, wsm);
    qkv_kernel<<<dim3(6, 256), 256, 0, stream>>>(x, Wts, Wtq, wsm, modes,
                                                 qws, kws, vws, gws);
    attn_kernel<<<dim3(2048, 3), 256, 0, stream>>>(qws, kws, vws, gws, maskws,
                                                   w1t, w2t, wsm, ohws);
    outproj_kernel<<<dim3(6, 256), 256, 0, stream>>>(ohws, wot, wsm, out);
}